// Round 10
// baseline (575.550 us; speedup 1.0000x reference)
//
#include <hip/hip_runtime.h>
#include <hip/hip_bf16.h>
#include <math.h>

#define Nn 10000
#define Ee 160000
#define ET 170000   // Ee + Nn (self loops)
#define LL 6

typedef short v8s __attribute__((ext_vector_type(8)));
typedef float v4f __attribute__((ext_vector_type(4)));
typedef float v2f __attribute__((ext_vector_type(2)));

__device__ __forceinline__ unsigned short f2bf(float v) {
    unsigned int b = __float_as_uint(v);
    b += 0x7fffu + ((b >> 16) & 1u);   // RNE
    return (unsigned short)(b >> 16);
}

// ---------------- node embedding: h = x @ node_w + node_b (fp32 + bf16 mirror) ----------------
__global__ void k_node_embed(const float* __restrict__ x, const float* __restrict__ nw,
                             const float* __restrict__ nb, float* __restrict__ h,
                             unsigned short* __restrict__ hb) {
    int idx = blockIdx.x * 256 + threadIdx.x;
    if (idx >= Nn * 128) return;
    int n = idx >> 7, c = idx & 127;
    const float* xr = x + (size_t)n * 8;
    float acc = nb[c];
#pragma unroll
    for (int k = 0; k < 8; k++) acc += xr[k] * nw[k * 128 + c];
    h[idx] = acc;
    hb[idx] = f2bf(acc);
}

// ---------------- small precompute: E1[128][8] = {M1[0..3][k], d1[k], 0,0,0} ----------------
__global__ void k_small(const float* __restrict__ vnfc, const float* __restrict__ vw,
                        const float* __restrict__ vb, const float* __restrict__ eab,
                        const float* __restrict__ a1w, const float* __restrict__ a1b,
                        const float* __restrict__ eaw, float* __restrict__ E1) {
    __shared__ float vr[128];
    __shared__ float sM1[512];
    __shared__ float sd1[128];
    int t = threadIdx.x;   // 512
    if (t < 128) {
        float a = vb[t];
#pragma unroll
        for (int k = 0; k < 6; k++) a += vnfc[k] * vw[k * 128 + t];
        vr[t] = a;
    }
    __syncthreads();
    if (t < 128) {
        float a = a1b[t];
        for (int k = 0; k < 128; k++) a += eab[k] * a1w[k * 128 + t];
        for (int k = 0; k < 128; k++) a += vr[k] * a1w[(128 + k) * 128 + t];
        sd1[t] = a;
    }
    {
        int r = t >> 7, j = t & 127;
        float a = 0.f;
        for (int k = 0; k < 128; k++) a += eaw[r * 128 + k] * a1w[k * 128 + j];
        sM1[r * 128 + j] = a;
    }
    __syncthreads();
    if (t < 128) {
        E1[t * 8 + 0] = sM1[t];
        E1[t * 8 + 1] = sM1[128 + t];
        E1[t * 8 + 2] = sM1[256 + t];
        E1[t * 8 + 3] = sM1[384 + t];
        E1[t * 8 + 4] = sd1[t];
        E1[t * 8 + 5] = 0.f; E1[t * 8 + 6] = 0.f; E1[t * 8 + 7] = 0.f;
    }
}

// ---------------- B matrices: Bs/Bd/Be [L][128][4] ----------------
__global__ void k_bmat(const float* __restrict__ glw, const float* __restrict__ gas,
                       const float* __restrict__ gad, const float* __restrict__ glew,
                       const float* __restrict__ gae, float* __restrict__ Bs,
                       float* __restrict__ Bd, float* __restrict__ Be) {
    int idx = blockIdx.x * 256 + threadIdx.x;
    if (idx >= LL * 128 * 4) return;
    int hh = idx & 3, k = (idx >> 2) & 127, l = idx >> 9;
    const float* lwp = glw  + (size_t)l * 65536 + k * 512 + hh * 128;
    const float* lep = glew + (size_t)l * 65536 + k * 512 + hh * 128;
    const float* sp = gas + l * 512 + hh * 128;
    const float* dp = gad + l * 512 + hh * 128;
    const float* ep = gae + l * 512 + hh * 128;
    float s1 = 0, s2 = 0, s3 = 0;
    for (int c = 0; c < 128; c++) {
        float lv = lwp[c];
        s1 += lv * sp[c];
        s2 += lv * dp[c];
        s3 += lep[c] * ep[c];
    }
    Bs[idx] = s1; Bd[idx] = s2; Be[idx] = s3;
}

// ---- WsumT[l][c][kk] bf16 = 0.25 * lw_l[kk&127][ (kk>>7)*128 + c ]  (B^T for k_post) ----
__global__ void k_wsum(const float* __restrict__ glw, unsigned short* __restrict__ WsumT) {
    int idx = blockIdx.x * 256 + threadIdx.x;
    if (idx >= LL * 128 * 512) return;
    int kk = idx & 511;
    int c = (idx >> 9) & 127;
    int l = idx >> 16;
    float v = 0.25f * glw[(size_t)l * 65536 + (size_t)(kk & 127) * 512 + (kk >> 7) * 128 + c];
    WsumT[(size_t)l * 65536 + (size_t)c * 512 + kk] = f2bf(v);
}

// ---------------- PB[4][24], cB[24]: fold ea_proj through Be ----------------
__global__ void k_pb(const float* __restrict__ eaw, const float* __restrict__ eab,
                     const float* __restrict__ Be, float* __restrict__ PB,
                     float* __restrict__ cB) {
    int t = threadIdx.x;
    if (t >= 24) return;
    int l = t >> 2, hh = t & 3;
    const float* bp = Be + l * 512 + hh;
    float s0 = 0, s1 = 0, s2 = 0, s3 = 0, sc = 0;
    for (int k = 0; k < 128; k++) {
        float bv = bp[k * 4];
        s0 += eaw[0 * 128 + k] * bv;
        s1 += eaw[1 * 128 + k] * bv;
        s2 += eaw[2 * 128 + k] * bv;
        s3 += eaw[3 * 128 + k] * bv;
        sc += eab[k] * bv;
    }
    PB[0 * 24 + t] = s0; PB[1 * 24 + t] = s1;
    PB[2 * 24 + t] = s2; PB[3 * 24 + t] = s3;
    cB[t] = sc;
}

// ---- edge gate MLP: LDS weights; 256 edges/block, 4/lane, packed-fp32 payload ----
__global__ __launch_bounds__(256) void k_edge(
    const float* __restrict__ ea, const float* __restrict__ E1,
    const float* __restrict__ a2w, const float* __restrict__ a2b,
    const float* __restrict__ a3w, const float* __restrict__ a3b,
    const float* __restrict__ PB, const float* __restrict__ cB,
    float* __restrict__ aleT, float* __restrict__ gsum) {
    __shared__ float sw2[128 * 64];   // 32 KB, [k][j]
    __shared__ float4 sM[128];
    __shared__ float sD[128];
    __shared__ float prs[4][256];
    __shared__ float gsh[256];
    int t = threadIdx.x;
    int lane = t & 63;
    int p = t >> 6;
    int ps = __builtin_amdgcn_readfirstlane(p);
    for (int z = t; z < 2048; z += 256) ((float4*)sw2)[z] = ((const float4*)a2w)[z];
    if (t < 128) { sM[t] = *(const float4*)(E1 + t * 8); sD[t] = E1[t * 8 + 4]; }
    __syncthreads();
    int eb = blockIdx.x * 256 + lane;
    float4 ev[4];
#pragma unroll
    for (int r = 0; r < 4; r++) ev[r] = *(const float4*)(ea + (size_t)(eb + r * 64) * 4);
    v2f acc[4][8];
#pragma unroll
    for (int j = 0; j < 8; j++) {
        v2f b = {a2b[ps * 16 + 2 * j], a2b[ps * 16 + 2 * j + 1]};
#pragma unroll
        for (int r = 0; r < 4; r++) acc[r][j] = b;
    }
    const float* w2base = sw2 + ps * 16;
    for (int k = 0; k < 128; k++) {
        float4 m = sM[k];
        float dk = sD[k];
        v2f xx[4];
#pragma unroll
        for (int r = 0; r < 4; r++) {
            float xv = fmaxf(dk + ev[r].x * m.x + ev[r].y * m.y + ev[r].z * m.z + ev[r].w * m.w, 0.f);
            xx[r][0] = xv; xx[r][1] = xv;
        }
        const float* w2r = w2base + k * 64;
#pragma unroll
        for (int j4 = 0; j4 < 4; j4++) {
            float4 wv = *(const float4*)(w2r + j4 * 4);
            v2f w01 = {wv.x, wv.y}, w23 = {wv.z, wv.w};
#pragma unroll
            for (int r = 0; r < 4; r++) {
                acc[r][2 * j4]     += xx[r] * w01;
                acc[r][2 * j4 + 1] += xx[r] * w23;
            }
        }
    }
#pragma unroll
    for (int r = 0; r < 4; r++) {
        float pr = 0.f;
#pragma unroll
        for (int j = 0; j < 8; j++) {
            pr += fmaxf(acc[r][j][0], 0.f) * a3w[ps * 16 + 2 * j];
            pr += fmaxf(acc[r][j][1], 0.f) * a3w[ps * 16 + 2 * j + 1];
        }
        prs[p][r * 64 + lane] = pr;
    }
    __syncthreads();
    if (p == 0) {
        float v0 = 0.f, v1 = 0.f, v2 = 0.f, v3 = 0.f, v4 = 0.f;
#pragma unroll
        for (int rep = 0; rep < 4; rep++) {
            int le = rep * 64 + lane;
            float tot = prs[0][le] + prs[1][le] + prs[2][le] + prs[3][le] + a3b[0];
            float g = 1.f / (1.f + __expf(-tot));
            gsh[le] = g;
            float4 evv = ev[rep];
            v0 += g; v1 += g * evv.x; v2 += g * evv.y; v3 += g * evv.z; v4 += g * evv.w;
        }
#pragma unroll
        for (int d = 32; d > 0; d >>= 1) {
            v0 += __shfl_down(v0, d); v1 += __shfl_down(v1, d); v2 += __shfl_down(v2, d);
            v3 += __shfl_down(v3, d); v4 += __shfl_down(v4, d);
        }
        if (lane == 0) {
            atomicAdd(&gsum[0], v0); atomicAdd(&gsum[1], v1); atomicAdd(&gsum[2], v2);
            atomicAdd(&gsum[3], v3); atomicAdd(&gsum[4], v4);
        }
    }
    __syncthreads();
#pragma unroll
    for (int rep = 0; rep < 2; rep++) {
        int i4 = (rep == 0) ? ps : (ps < 2 ? ps + 4 : -1);
        if (i4 >= 0) {
            float4 c  = *(const float4*)(cB + i4 * 4);
            float4 p0 = *(const float4*)(PB + 0 * 24 + i4 * 4);
            float4 p1 = *(const float4*)(PB + 1 * 24 + i4 * 4);
            float4 p2 = *(const float4*)(PB + 2 * 24 + i4 * 4);
            float4 p3 = *(const float4*)(PB + 3 * 24 + i4 * 4);
#pragma unroll
            for (int r = 0; r < 4; r++) {
                float g = gsh[r * 64 + lane];
                float4 evv = ev[r];
                float4 o;
                o.x = g * (c.x + evv.x * p0.x + evv.y * p1.x + evv.z * p2.x + evv.w * p3.x);
                o.y = g * (c.y + evv.x * p0.y + evv.y * p1.y + evv.z * p2.y + evv.w * p3.y);
                o.z = g * (c.z + evv.x * p0.z + evv.y * p1.z + evv.z * p2.z + evv.w * p3.z);
                o.w = g * (c.w + evv.x * p0.w + evv.y * p1.w + evv.z * p2.w + evv.w * p3.w);
                *(float4*)(aleT + (size_t)i4 * Ee * 4 + (size_t)(eb + r * 64) * 4) = o;
            }
        }
    }
}

// ---------------- loop-edge al_e from G,S sums ----------------
__global__ void k_lale(const float* __restrict__ gsum, const float* __restrict__ PB,
                       const float* __restrict__ cB, float* __restrict__ lale) {
    int t = threadIdx.x;
    if (t >= 24) return;
    float s = gsum[0] * cB[t] + gsum[1] * PB[t] + gsum[2] * PB[24 + t]
            + gsum[3] * PB[48 + t] + gsum[4] * PB[72 + t];
    lale[t] = s * (1.0f / Ee);
}

// ---------------- counting sort by dst: hist / scan / scatter ----------------
__global__ void k_hist(const int* __restrict__ ei, int* __restrict__ hist) {
    int i = blockIdx.x * 256 + threadIdx.x;
    if (i >= ET) return;
    int d = (i < Ee) ? ei[Ee + i] : (i - Ee);
    atomicAdd(&hist[d], 1);
}

__global__ __launch_bounds__(1024) void k_scan(const int* __restrict__ hist,
                                               int* __restrict__ seg, int* __restrict__ pos) {
    __shared__ int wsums[16];
    __shared__ int carry_s;
    int t = threadIdx.x;
    int lane = t & 63, wid = t >> 6;
    if (t == 0) { carry_s = 0; seg[0] = 0; }
    __syncthreads();
    for (int base = 0; base < Nn; base += 1024) {
        int idx = base + t;
        int v = (idx < Nn) ? hist[idx] : 0;
        int sc = v;
#pragma unroll
        for (int d = 1; d < 64; d <<= 1) {
            int up = __shfl_up(sc, d);
            if (lane >= d) sc += up;
        }
        if (lane == 63) wsums[wid] = sc;
        __syncthreads();
        if (wid == 0) {
            int wv = (lane < 16) ? wsums[lane] : 0;
            int wsc = wv;
#pragma unroll
            for (int d = 1; d < 16; d <<= 1) {
                int up = __shfl_up(wsc, d);
                if (lane >= d) wsc += up;
            }
            if (lane < 16) wsums[lane] = wsc - wv;
        }
        __syncthreads();
        int carry = carry_s;
        int inc = sc + wsums[wid] + carry;
        if (idx < Nn) { seg[idx + 1] = inc; pos[idx] = inc - v; }
        __syncthreads();
        if (t == 1023) carry_s = inc;
        __syncthreads();
    }
}

__global__ void k_scatter(const int* __restrict__ ei, int* __restrict__ pos,
                          int2* __restrict__ pse) {
    int i = blockIdx.x * 256 + threadIdx.x;
    if (i >= ET) return;
    int s, d;
    if (i < Ee) { s = ei[i]; d = ei[Ee + i]; } else { s = d = i - Ee; }
    int idx = atomicAdd(&pos[d], 1);
    pse[idx] = make_int2(s, i);
}

// ---------------- per-layer: als/ald = h @ Bs/Bd ----------------
__global__ void k_ab(const float* __restrict__ h, const float* __restrict__ Bs_l,
                     const float* __restrict__ Bd_l, float* __restrict__ als,
                     float* __restrict__ ald) {
    int idx = blockIdx.x * 256 + threadIdx.x;
    if (idx >= Nn * 8) return;
    int n = idx >> 3, slot = idx & 7;
    const float* B = (slot < 4) ? Bs_l : Bd_l;
    int hh = slot & 3;
    const float4* hr = (const float4*)(h + (size_t)n * 128);
    float s = 0.f;
#pragma unroll 8
    for (int kb = 0; kb < 32; kb++) {
        float4 hv = hr[kb];
        s += hv.x * B[(4 * kb + 0) * 4 + hh] + hv.y * B[(4 * kb + 1) * 4 + hh]
           + hv.z * B[(4 * kb + 2) * 4 + hh] + hv.w * B[(4 * kb + 3) * 4 + hh];
    }
    if (slot < 4) als[n * 4 + hh] = s;
    else          ald[n * 4 + hh] = s;
}

// ---- per-layer agg in h-space: softmax + per-head gather of hb rows -> aggb bf16 ----
__global__ __launch_bounds__(256) void k_agg2(
    const int2* __restrict__ pse, const int* __restrict__ seg,
    const float* __restrict__ als, const float* __restrict__ ald,
    const float* __restrict__ aleT_l, const float* __restrict__ lale_l,
    const unsigned short* __restrict__ hb, unsigned short* __restrict__ aggb) {
    __shared__ float lgS[2][512];
    __shared__ int srcS[2][128];
    __shared__ float msS[2][2][8];
    __shared__ float part[2][512];
    int t = threadIdx.x;
    int lane = t & 63;
    int wv = (t >> 6) & 1;
    int w = t >> 7;
    int n = blockIdx.x * 2 + w;
    int start = seg[n], end = seg[n + 1];
    int deg = end - start;
    int half = (deg + 1) >> 1;
    int s0 = start + wv * half;
    int e0 = wv ? end : start + half;
    int h1 = lane & 3;
    float llh1 = lale_l[h1];
    float a1d = ald[n * 4 + h1];
    float m = -INFINITY, ss = 0.f;
    for (int i = s0 + (lane >> 2); i < e0; i += 16) {
        int idx = i - start;
        int2 se = pse[i];
        float alev = se.y < Ee ? aleT_l[(size_t)se.y * 4 + h1] : llh1;
        float av = als[se.x * 4 + h1] + a1d + alev;
        av = av > 0.f ? av : 0.2f * av;
        if (idx < 128) {
            lgS[w][idx * 4 + h1] = av;
            if (h1 == 0) srcS[w][idx] = se.x;
        }
        if (av > m) { ss = ss * __expf(m - av) + 1.f; m = av; }
        else ss += __expf(av - m);
    }
#pragma unroll
    for (int d = 4; d <= 32; d <<= 1) {
        float mo = __shfl_xor(m, d), so = __shfl_xor(ss, d);
        float mm = fmaxf(m, mo);
        float sv = 0.f;
        if (m > -INFINITY) sv += ss * __expf(m - mm);
        if (mo > -INFINITY) sv += so * __expf(mo - mm);
        m = mm; ss = sv;
    }
    if (lane < 4) { msS[w][wv][lane] = m; msS[w][wv][4 + lane] = ss; }
    __syncthreads();
    {
        float mo = msS[w][1 - wv][h1], so = msS[w][1 - wv][4 + h1];
        float mm = fmaxf(m, mo);
        float sv = 0.f;
        if (m > -INFINITY) sv += ss * __expf(m - mm);
        if (mo > -INFINITY) sv += so * __expf(mo - mm);
        m = mm; ss = sv;
    }
    float mh0 = __shfl(m, 0), mh1 = __shfl(m, 1), mh2 = __shfl(m, 2), mh3 = __shfl(m, 3);
    float iv0 = 1.f / (__shfl(ss, 0) + 1e-16f), iv1 = 1.f / (__shfl(ss, 1) + 1e-16f);
    float iv2 = 1.f / (__shfl(ss, 2) + 1e-16f), iv3 = 1.f / (__shfl(ss, 3) + 1e-16f);
    int lo = wv * half;
    int hi = min(wv ? deg : half, 128);
    for (int z = lo + lane; z < hi; z += 64) {
        float4 lg = *(float4*)&lgS[w][z * 4];
        lg.x = __expf(lg.x - mh0) * iv0;
        lg.y = __expf(lg.y - mh1) * iv1;
        lg.z = __expf(lg.z - mh2) * iv2;
        lg.w = __expf(lg.w - mh3) * iv3;
        *(float4*)&lgS[w][z * 4] = lg;
    }
    int hp = lane >> 4;
    int cch = (lane & 15) * 8;       // channels of the 128-ch h row
    float4 acc0 = make_float4(0.f, 0.f, 0.f, 0.f);
    float4 acc1 = make_float4(0.f, 0.f, 0.f, 0.f);
    int i2 = lo;
    for (; i2 + 2 <= hi; i2 += 2) {
        int sa = srcS[w][i2], sb = srcS[w][i2 + 1];
        float wg0 = lgS[w][i2 * 4 + hp], wg1 = lgS[w][i2 * 4 + 4 + hp];
        uint4 u0 = *(const uint4*)(hb + (size_t)sa * 128 + cch);
        uint4 u1 = *(const uint4*)(hb + (size_t)sb * 128 + cch);
        acc0.x += wg0 * __uint_as_float(u0.x << 16) + wg1 * __uint_as_float(u1.x << 16);
        acc0.y += wg0 * __uint_as_float(u0.x & 0xffff0000u) + wg1 * __uint_as_float(u1.x & 0xffff0000u);
        acc0.z += wg0 * __uint_as_float(u0.y << 16) + wg1 * __uint_as_float(u1.y << 16);
        acc0.w += wg0 * __uint_as_float(u0.y & 0xffff0000u) + wg1 * __uint_as_float(u1.y & 0xffff0000u);
        acc1.x += wg0 * __uint_as_float(u0.z << 16) + wg1 * __uint_as_float(u1.z << 16);
        acc1.y += wg0 * __uint_as_float(u0.z & 0xffff0000u) + wg1 * __uint_as_float(u1.z & 0xffff0000u);
        acc1.z += wg0 * __uint_as_float(u0.w << 16) + wg1 * __uint_as_float(u1.w << 16);
        acc1.w += wg0 * __uint_as_float(u0.w & 0xffff0000u) + wg1 * __uint_as_float(u1.w & 0xffff0000u);
    }
    if (i2 < hi) {
        int sa = srcS[w][i2];
        float wg0 = lgS[w][i2 * 4 + hp];
        uint4 u0 = *(const uint4*)(hb + (size_t)sa * 128 + cch);
        acc0.x += wg0 * __uint_as_float(u0.x << 16);
        acc0.y += wg0 * __uint_as_float(u0.x & 0xffff0000u);
        acc0.z += wg0 * __uint_as_float(u0.y << 16);
        acc0.w += wg0 * __uint_as_float(u0.y & 0xffff0000u);
        acc1.x += wg0 * __uint_as_float(u0.z << 16);
        acc1.y += wg0 * __uint_as_float(u0.z & 0xffff0000u);
        acc1.z += wg0 * __uint_as_float(u0.w << 16);
        acc1.w += wg0 * __uint_as_float(u0.w & 0xffff0000u);
    }
    // tail (deg > 128: recompute)
    float mhp = hp == 0 ? mh0 : hp == 1 ? mh1 : hp == 2 ? mh2 : mh3;
    float ivp = hp == 0 ? iv0 : hp == 1 ? iv1 : hp == 2 ? iv2 : iv3;
    for (int i = start + max(lo, 128); i < e0; i++) {
        int2 se = pse[i];
        float alev = se.y < Ee ? aleT_l[(size_t)se.y * 4 + hp] : lale_l[hp];
        float av = als[se.x * 4 + hp] + ald[n * 4 + hp] + alev;
        av = av > 0.f ? av : 0.2f * av;
        float wg0 = __expf(av - mhp) * ivp;
        uint4 u0 = *(const uint4*)(hb + (size_t)se.x * 128 + cch);
        acc0.x += wg0 * __uint_as_float(u0.x << 16);
        acc0.y += wg0 * __uint_as_float(u0.x & 0xffff0000u);
        acc0.z += wg0 * __uint_as_float(u0.y << 16);
        acc0.w += wg0 * __uint_as_float(u0.y & 0xffff0000u);
        acc1.x += wg0 * __uint_as_float(u0.z << 16);
        acc1.y += wg0 * __uint_as_float(u0.z & 0xffff0000u);
        acc1.z += wg0 * __uint_as_float(u0.w << 16);
        acc1.w += wg0 * __uint_as_float(u0.w & 0xffff0000u);
    }
    // combine the 2 waves; out slot for lane = lane*8 of 512 (= hp*128 + cch)
    if (wv == 1) {
        *(float4*)&part[w][lane * 8] = acc0;
        *(float4*)&part[w][lane * 8 + 4] = acc1;
    }
    __syncthreads();
    if (wv == 0) {
        float4 p0 = *(const float4*)&part[w][lane * 8];
        float4 p1 = *(const float4*)&part[w][lane * 8 + 4];
        acc0.x += p0.x; acc0.y += p0.y; acc0.z += p0.z; acc0.w += p0.w;
        acc1.x += p1.x; acc1.y += p1.y; acc1.z += p1.z; acc1.w += p1.w;
        ushort4 q0, q1;
        q0.x = f2bf(acc0.x); q0.y = f2bf(acc0.y); q0.z = f2bf(acc0.z); q0.w = f2bf(acc0.w);
        q1.x = f2bf(acc1.x); q1.y = f2bf(acc1.y); q1.z = f2bf(acc1.z); q1.w = f2bf(acc1.w);
        *(ushort4*)(aggb + (size_t)n * 512 + lane * 8) = q0;
        *(ushort4*)(aggb + (size_t)n * 512 + lane * 8 + 4) = q1;
    }
}

// ---- per-layer: h_new = LN(relu(aggcat @ Wsum + gbias) + h) via MFMA ----
__global__ __launch_bounds__(256) void k_post(
    const unsigned short* __restrict__ aggb, const unsigned short* __restrict__ WsumT_l,
    const float* __restrict__ gbias, const float* __restrict__ lnsc,
    const float* __restrict__ lnbi, float* __restrict__ h,
    unsigned short* __restrict__ hb) {
    int t = threadIdx.x;
    int lane = t & 63, w = t >> 6;
    int n0 = (blockIdx.x * 4 + w) * 16;
    if (n0 >= Nn) return;
    int m = lane & 15, q = lane >> 4;
    v4f acc[8];
#pragma unroll
    for (int nt = 0; nt < 8; nt++) acc[nt] = (v4f){0.f, 0.f, 0.f, 0.f};
    const unsigned short* arow = aggb + (size_t)(n0 + m) * 512 + q * 8;
#pragma unroll 4
    for (int ks = 0; ks < 16; ks++) {
        v8s fa = *(const v8s*)(arow + ks * 32);
#pragma unroll
        for (int nt = 0; nt < 8; nt++) {
            int col = nt * 16 + m;
            v8s fb = *(const v8s*)(WsumT_l + (size_t)col * 512 + ks * 32 + q * 8);
            acc[nt] = __builtin_amdgcn_mfma_f32_16x16x32_bf16(fa, fb, acc[nt], 0, 0, 0);
        }
    }
    // epilogue: rows n0+q*4+r, cols nt*16+m
    float v[8][4];
    float s1[4] = {0.f, 0.f, 0.f, 0.f}, s2[4] = {0.f, 0.f, 0.f, 0.f};
#pragma unroll
    for (int nt = 0; nt < 8; nt++) {
        int col = nt * 16 + m;
        float b = gbias[col];
#pragma unroll
        for (int r = 0; r < 4; r++) {
            int row = n0 + q * 4 + r;
            float val = h[(size_t)row * 128 + col] + fmaxf(acc[nt][r] + b, 0.f);
            v[nt][r] = val;
            s1[r] += val; s2[r] += val * val;
        }
    }
#pragma unroll
    for (int d = 1; d <= 8; d <<= 1) {
#pragma unroll
        for (int r = 0; r < 4; r++) {
            s1[r] += __shfl_xor(s1[r], d);
            s2[r] += __shfl_xor(s2[r], d);
        }
    }
#pragma unroll
    for (int r = 0; r < 4; r++) {
        float mean = s1[r] * (1.f / 128.f);
        float var = s2[r] * (1.f / 128.f) - mean * mean;
        float rinv = rsqrtf(var + 1e-5f);
        int row = n0 + q * 4 + r;
#pragma unroll
        for (int nt = 0; nt < 8; nt++) {
            int col = nt * 16 + m;
            float o = (v[nt][r] - mean) * rinv * lnsc[col] + lnbi[col];
            h[(size_t)row * 128 + col] = o;
            hb[(size_t)row * 128 + col] = f2bf(o);
        }
    }
}

// ---------------- output projection ----------------
__global__ __launch_bounds__(256) void k_out(
    const float* __restrict__ h, const float* __restrict__ ow,
    const float* __restrict__ ob, float* __restrict__ out) {
    __shared__ float4 hs4[8][32];
    int t = threadIdx.x;
    int n0 = blockIdx.x * 8;
    if (t < 256) {
        int i = t >> 5, kb = t & 31;
        hs4[i][kb] = *(const float4*)(h + (size_t)(n0 + i) * 128 + 4 * kb);
    }
    __syncthreads();
    float acc[8] = {0, 0, 0, 0, 0, 0, 0, 0};
    for (int kb = 0; kb < 32; kb++) {
        float w0 = ow[(4 * kb + 0) * 256 + t];
        float w1 = ow[(4 * kb + 1) * 256 + t];
        float w2 = ow[(4 * kb + 2) * 256 + t];
        float w3 = ow[(4 * kb + 3) * 256 + t];
#pragma unroll
        for (int i = 0; i < 8; i++) {
            float4 hv = hs4[i][kb];
            acc[i] += hv.x * w0 + hv.y * w1 + hv.z * w2 + hv.w * w3;
        }
    }
    float b = ob[t];
#pragma unroll
    for (int i = 0; i < 8; i++) out[(size_t)(n0 + i) * 256 + t] = acc[i] + b;
}

extern "C" void kernel_launch(void* const* d_in, const int* in_sizes, int n_in,
                              void* d_out, int out_size, void* d_ws, size_t ws_size,
                              hipStream_t stream) {
    const float* x    = (const float*)d_in[0];
    const int*   ei   = (const int*)d_in[1];
    const float* ea   = (const float*)d_in[2];
    const float* vnfc = (const float*)d_in[3];
    const float* nw   = (const float*)d_in[4];
    const float* nb   = (const float*)d_in[5];
    const float* eaw  = (const float*)d_in[6];
    const float* eab  = (const float*)d_in[7];
    const float* vw   = (const float*)d_in[8];
    const float* vb   = (const float*)d_in[9];
    const float* a1w  = (const float*)d_in[10];
    const float* a1b  = (const float*)d_in[11];
    const float* a2w  = (const float*)d_in[12];
    const float* a2b  = (const float*)d_in[13];
    const float* a3w  = (const float*)d_in[14];
    const float* a3b  = (const float*)d_in[15];
    const float* glw  = (const float*)d_in[16];
    const float* gas  = (const float*)d_in[17];
    const float* gad  = (const float*)d_in[18];
    const float* glew = (const float*)d_in[19];
    const float* gae  = (const float*)d_in[20];
    const float* gb   = (const float*)d_in[21];
    const float* lnsc = (const float*)d_in[22];
    const float* lnbi = (const float*)d_in[23];
    const float* ow   = (const float*)d_in[24];
    const float* ob   = (const float*)d_in[25];
    float* out = (float*)d_out;

    char* w = (char*)d_ws;
    size_t o = 0;
    auto allocf = [&](size_t cnt) { float* p = (float*)(w + o); o += ((cnt * 4 + 255) / 256) * 256; return p; };
    auto alloci = [&](size_t cnt) { int* p = (int*)(w + o); o += ((cnt * 4 + 255) / 256) * 256; return p; };
    auto allocu = [&](size_t cnt) { unsigned short* p = (unsigned short*)(w + o); o += ((cnt * 2 + 255) / 256) * 256; return p; };
    float* h      = allocf((size_t)Nn * 128);
    unsigned short* hb    = allocu((size_t)Nn * 128);
    unsigned short* aggb  = allocu((size_t)Nn * 512);
    unsigned short* WsumT = allocu((size_t)LL * 128 * 512);
    float* als    = allocf((size_t)Nn * 4);
    float* ald    = allocf((size_t)Nn * 4);
    float* aleT   = allocf((size_t)LL * Ee * 4);
    float* Bs     = allocf(3072);
    float* Bd     = allocf(3072);
    float* Be     = allocf(3072);
    float* E1     = allocf(1024);
    float* PB     = allocf(96);
    float* cB     = allocf(24);
    float* gsum   = allocf(8);
    float* lale   = allocf(32);
    int* seg  = alloci(Nn + 1);
    int* hist = alloci(Nn);
    int* pos  = alloci(Nn);
    int2* pse = (int2*)alloci((size_t)ET * 2);

    hipMemsetAsync(hist, 0, Nn * sizeof(int), stream);
    hipMemsetAsync(gsum, 0, 8 * sizeof(float), stream);

    k_node_embed<<<(Nn * 128 + 255) / 256, 256, 0, stream>>>(x, nw, nb, h, hb);
    k_small<<<1, 512, 0, stream>>>(vnfc, vw, vb, eab, a1w, a1b, eaw, E1);
    k_bmat<<<(LL * 128 * 4 + 255) / 256, 256, 0, stream>>>(glw, gas, gad, glew, gae, Bs, Bd, Be);
    k_wsum<<<(LL * 128 * 512 + 255) / 256, 256, 0, stream>>>(glw, WsumT);
    k_pb<<<1, 32, 0, stream>>>(eaw, eab, Be, PB, cB);
    k_edge<<<Ee / 256, 256, 0, stream>>>(ea, E1, a2w, a2b, a3w, a3b, PB, cB, aleT, gsum);
    k_hist<<<(ET + 255) / 256, 256, 0, stream>>>(ei, hist);
    k_scan<<<1, 1024, 0, stream>>>(hist, seg, pos);
    k_scatter<<<(ET + 255) / 256, 256, 0, stream>>>(ei, pos, pse);
    k_lale<<<1, 32, 0, stream>>>(gsum, PB, cB, lale);
    for (int l = 0; l < LL; l++) {
        k_ab<<<(Nn * 8 + 255) / 256, 256, 0, stream>>>(h, Bs + l * 512, Bd + l * 512, als, ald);
        k_agg2<<<Nn / 2, 256, 0, stream>>>(pse, seg, als, ald, aleT + (size_t)l * Ee * 4,
                                           lale + l * 4, hb, aggb);
        k_post<<<(625 + 3) / 4, 256, 0, stream>>>(aggb, WsumT + (size_t)l * 65536,
                                                  gb + l * 128, lnsc + l * 128, lnbi + l * 128,
                                                  h, hb);
    }
    k_out<<<Nn / 8, 256, 0, stream>>>(h, ow, ob, out);
}

// Round 11
// 559.567 us; speedup vs baseline: 1.0286x; 1.0286x over previous
//
#include <hip/hip_runtime.h>
#include <hip/hip_bf16.h>
#include <math.h>

#define Nn 10000
#define Ee 160000
#define ET 170000   // Ee + Nn (self loops)
#define LL 6

typedef short v8s __attribute__((ext_vector_type(8)));
typedef float v4f __attribute__((ext_vector_type(4)));
typedef float v2f __attribute__((ext_vector_type(2)));

__device__ __forceinline__ unsigned short f2bf(float v) {
    unsigned int b = __float_as_uint(v);
    b += 0x7fffu + ((b >> 16) & 1u);   // RNE
    return (unsigned short)(b >> 16);
}
__device__ __forceinline__ float bflo(unsigned int u) { return __uint_as_float(u << 16); }
__device__ __forceinline__ float bfhi(unsigned int u) { return __uint_as_float(u & 0xffff0000u); }

// ---------------- node embedding: h = x @ node_w + node_b (fp32 + bf16 mirror) ----------------
__global__ void k_node_embed(const float* __restrict__ x, const float* __restrict__ nw,
                             const float* __restrict__ nb, float* __restrict__ h,
                             unsigned short* __restrict__ hb) {
    int idx = blockIdx.x * 256 + threadIdx.x;
    if (idx >= Nn * 128) return;
    int n = idx >> 7, c = idx & 127;
    const float* xr = x + (size_t)n * 8;
    float acc = nb[c];
#pragma unroll
    for (int k = 0; k < 8; k++) acc += xr[k] * nw[k * 128 + c];
    h[idx] = acc;
    hb[idx] = f2bf(acc);
}

// ---------------- small precompute: E1[128][8] = {M1[0..3][k], d1[k], 0,0,0} ----------------
__global__ void k_small(const float* __restrict__ vnfc, const float* __restrict__ vw,
                        const float* __restrict__ vb, const float* __restrict__ eab,
                        const float* __restrict__ a1w, const float* __restrict__ a1b,
                        const float* __restrict__ eaw, float* __restrict__ E1) {
    __shared__ float vr[128];
    __shared__ float sM1[512];
    __shared__ float sd1[128];
    int t = threadIdx.x;   // 512
    if (t < 128) {
        float a = vb[t];
#pragma unroll
        for (int k = 0; k < 6; k++) a += vnfc[k] * vw[k * 128 + t];
        vr[t] = a;
    }
    __syncthreads();
    if (t < 128) {
        float a = a1b[t];
        for (int k = 0; k < 128; k++) a += eab[k] * a1w[k * 128 + t];
        for (int k = 0; k < 128; k++) a += vr[k] * a1w[(128 + k) * 128 + t];
        sd1[t] = a;
    }
    {
        int r = t >> 7, j = t & 127;
        float a = 0.f;
        for (int k = 0; k < 128; k++) a += eaw[r * 128 + k] * a1w[k * 128 + j];
        sM1[r * 128 + j] = a;
    }
    __syncthreads();
    if (t < 128) {
        E1[t * 8 + 0] = sM1[t];
        E1[t * 8 + 1] = sM1[128 + t];
        E1[t * 8 + 2] = sM1[256 + t];
        E1[t * 8 + 3] = sM1[384 + t];
        E1[t * 8 + 4] = sd1[t];
        E1[t * 8 + 5] = 0.f; E1[t * 8 + 6] = 0.f; E1[t * 8 + 7] = 0.f;
    }
}

// ---------------- B matrices: Bs/Bd/Be [L][128][4] ----------------
__global__ void k_bmat(const float* __restrict__ glw, const float* __restrict__ gas,
                       const float* __restrict__ gad, const float* __restrict__ glew,
                       const float* __restrict__ gae, float* __restrict__ Bs,
                       float* __restrict__ Bd, float* __restrict__ Be) {
    int idx = blockIdx.x * 256 + threadIdx.x;
    if (idx >= LL * 128 * 4) return;
    int hh = idx & 3, k = (idx >> 2) & 127, l = idx >> 9;
    const float* lwp = glw  + (size_t)l * 65536 + k * 512 + hh * 128;
    const float* lep = glew + (size_t)l * 65536 + k * 512 + hh * 128;
    const float* sp = gas + l * 512 + hh * 128;
    const float* dp = gad + l * 512 + hh * 128;
    const float* ep = gae + l * 512 + hh * 128;
    float s1 = 0, s2 = 0, s3 = 0;
    for (int c = 0; c < 128; c++) {
        float lv = lwp[c];
        s1 += lv * sp[c];
        s2 += lv * dp[c];
        s3 += lep[c] * ep[c];
    }
    Bs[idx] = s1; Bd[idx] = s2; Be[idx] = s3;
}

// ---- WsumT[l][c][kk] bf16 = 0.25 * lw_l[kk&127][ (kk>>7)*128 + c ]  (B^T for k_post) ----
__global__ void k_wsum(const float* __restrict__ glw, unsigned short* __restrict__ WsumT) {
    int idx = blockIdx.x * 256 + threadIdx.x;
    if (idx >= LL * 128 * 512) return;
    int kk = idx & 511;
    int c = (idx >> 9) & 127;
    int l = idx >> 16;
    float v = 0.25f * glw[(size_t)l * 65536 + (size_t)(kk & 127) * 512 + (kk >> 7) * 128 + c];
    WsumT[(size_t)l * 65536 + (size_t)c * 512 + kk] = f2bf(v);
}

// ---------------- PB[4][24], cB[24]: fold ea_proj through Be ----------------
__global__ void k_pb(const float* __restrict__ eaw, const float* __restrict__ eab,
                     const float* __restrict__ Be, float* __restrict__ PB,
                     float* __restrict__ cB) {
    int t = threadIdx.x;
    if (t >= 24) return;
    int l = t >> 2, hh = t & 3;
    const float* bp = Be + l * 512 + hh;
    float s0 = 0, s1 = 0, s2 = 0, s3 = 0, sc = 0;
    for (int k = 0; k < 128; k++) {
        float bv = bp[k * 4];
        s0 += eaw[0 * 128 + k] * bv;
        s1 += eaw[1 * 128 + k] * bv;
        s2 += eaw[2 * 128 + k] * bv;
        s3 += eaw[3 * 128 + k] * bv;
        sc += eab[k] * bv;
    }
    PB[0 * 24 + t] = s0; PB[1 * 24 + t] = s1;
    PB[2 * 24 + t] = s2; PB[3 * 24 + t] = s3;
    cB[t] = sc;
}

// ---- edge gate MLP: LDS weights; 256 edges/block, 4/lane, packed-fp32 payload ----
__global__ __launch_bounds__(256, 3) void k_edge(
    const float* __restrict__ ea, const float* __restrict__ E1,
    const float* __restrict__ a2w, const float* __restrict__ a2b,
    const float* __restrict__ a3w, const float* __restrict__ a3b,
    const float* __restrict__ PB, const float* __restrict__ cB,
    float* __restrict__ aleT, float* __restrict__ gsum) {
    __shared__ float sw2[128 * 64];   // 32 KB, [k][j]
    __shared__ float4 sM[128];
    __shared__ float sD[128];
    __shared__ float prs[4][256];
    __shared__ float gsh[256];
    int t = threadIdx.x;
    int lane = t & 63;
    int p = t >> 6;
    int ps = __builtin_amdgcn_readfirstlane(p);
    for (int z = t; z < 2048; z += 256) ((float4*)sw2)[z] = ((const float4*)a2w)[z];
    if (t < 128) { sM[t] = *(const float4*)(E1 + t * 8); sD[t] = E1[t * 8 + 4]; }
    __syncthreads();
    int eb = blockIdx.x * 256 + lane;
    float4 ev[4];
#pragma unroll
    for (int r = 0; r < 4; r++) ev[r] = *(const float4*)(ea + (size_t)(eb + r * 64) * 4);
    v2f acc[4][8];
#pragma unroll
    for (int j = 0; j < 8; j++) {
        v2f b = {a2b[ps * 16 + 2 * j], a2b[ps * 16 + 2 * j + 1]};
#pragma unroll
        for (int r = 0; r < 4; r++) acc[r][j] = b;
    }
    const float* w2base = sw2 + ps * 16;
    for (int k = 0; k < 128; k++) {
        float4 m = sM[k];
        float dk = sD[k];
        v2f xx[4];
#pragma unroll
        for (int r = 0; r < 4; r++) {
            float xv = fmaxf(dk + ev[r].x * m.x + ev[r].y * m.y + ev[r].z * m.z + ev[r].w * m.w, 0.f);
            xx[r][0] = xv; xx[r][1] = xv;
        }
        const float* w2r = w2base + k * 64;
#pragma unroll
        for (int j4 = 0; j4 < 4; j4++) {
            float4 wv = *(const float4*)(w2r + j4 * 4);
            v2f w01 = {wv.x, wv.y}, w23 = {wv.z, wv.w};
#pragma unroll
            for (int r = 0; r < 4; r++) {
                acc[r][2 * j4]     += xx[r] * w01;
                acc[r][2 * j4 + 1] += xx[r] * w23;
            }
        }
    }
#pragma unroll
    for (int r = 0; r < 4; r++) {
        float pr = 0.f;
#pragma unroll
        for (int j = 0; j < 8; j++) {
            pr += fmaxf(acc[r][j][0], 0.f) * a3w[ps * 16 + 2 * j];
            pr += fmaxf(acc[r][j][1], 0.f) * a3w[ps * 16 + 2 * j + 1];
        }
        prs[p][r * 64 + lane] = pr;
    }
    __syncthreads();
    if (p == 0) {
        float v0 = 0.f, v1 = 0.f, v2 = 0.f, v3 = 0.f, v4 = 0.f;
#pragma unroll
        for (int rep = 0; rep < 4; rep++) {
            int le = rep * 64 + lane;
            float tot = prs[0][le] + prs[1][le] + prs[2][le] + prs[3][le] + a3b[0];
            float g = 1.f / (1.f + __expf(-tot));
            gsh[le] = g;
            float4 evv = ev[rep];
            v0 += g; v1 += g * evv.x; v2 += g * evv.y; v3 += g * evv.z; v4 += g * evv.w;
        }
#pragma unroll
        for (int d = 32; d > 0; d >>= 1) {
            v0 += __shfl_down(v0, d); v1 += __shfl_down(v1, d); v2 += __shfl_down(v2, d);
            v3 += __shfl_down(v3, d); v4 += __shfl_down(v4, d);
        }
        if (lane == 0) {
            atomicAdd(&gsum[0], v0); atomicAdd(&gsum[1], v1); atomicAdd(&gsum[2], v2);
            atomicAdd(&gsum[3], v3); atomicAdd(&gsum[4], v4);
        }
    }
    __syncthreads();
#pragma unroll
    for (int rep = 0; rep < 2; rep++) {
        int i4 = (rep == 0) ? ps : (ps < 2 ? ps + 4 : -1);
        if (i4 >= 0) {
            float4 c  = *(const float4*)(cB + i4 * 4);
            float4 p0 = *(const float4*)(PB + 0 * 24 + i4 * 4);
            float4 p1 = *(const float4*)(PB + 1 * 24 + i4 * 4);
            float4 p2 = *(const float4*)(PB + 2 * 24 + i4 * 4);
            float4 p3 = *(const float4*)(PB + 3 * 24 + i4 * 4);
#pragma unroll
            for (int r = 0; r < 4; r++) {
                float g = gsh[r * 64 + lane];
                float4 evv = ev[r];
                float4 o;
                o.x = g * (c.x + evv.x * p0.x + evv.y * p1.x + evv.z * p2.x + evv.w * p3.x);
                o.y = g * (c.y + evv.x * p0.y + evv.y * p1.y + evv.z * p2.y + evv.w * p3.y);
                o.z = g * (c.z + evv.x * p0.z + evv.y * p1.z + evv.z * p2.z + evv.w * p3.z);
                o.w = g * (c.w + evv.x * p0.w + evv.y * p1.w + evv.z * p2.w + evv.w * p3.w);
                *(float4*)(aleT + (size_t)i4 * Ee * 4 + (size_t)(eb + r * 64) * 4) = o;
            }
        }
    }
}

// ---------------- loop-edge al_e from G,S sums ----------------
__global__ void k_lale(const float* __restrict__ gsum, const float* __restrict__ PB,
                       const float* __restrict__ cB, float* __restrict__ lale) {
    int t = threadIdx.x;
    if (t >= 24) return;
    float s = gsum[0] * cB[t] + gsum[1] * PB[t] + gsum[2] * PB[24 + t]
            + gsum[3] * PB[48 + t] + gsum[4] * PB[72 + t];
    lale[t] = s * (1.0f / Ee);
}

// ---------------- counting sort by dst: hist / scan / scatter ----------------
__global__ void k_hist(const int* __restrict__ ei, int* __restrict__ hist) {
    int i = blockIdx.x * 256 + threadIdx.x;
    if (i >= ET) return;
    int d = (i < Ee) ? ei[Ee + i] : (i - Ee);
    atomicAdd(&hist[d], 1);
}

__global__ __launch_bounds__(1024) void k_scan(const int* __restrict__ hist,
                                               int* __restrict__ seg, int* __restrict__ pos) {
    __shared__ int wsums[16];
    __shared__ int carry_s;
    int t = threadIdx.x;
    int lane = t & 63, wid = t >> 6;
    if (t == 0) { carry_s = 0; seg[0] = 0; }
    __syncthreads();
    for (int base = 0; base < Nn; base += 1024) {
        int idx = base + t;
        int v = (idx < Nn) ? hist[idx] : 0;
        int sc = v;
#pragma unroll
        for (int d = 1; d < 64; d <<= 1) {
            int up = __shfl_up(sc, d);
            if (lane >= d) sc += up;
        }
        if (lane == 63) wsums[wid] = sc;
        __syncthreads();
        if (wid == 0) {
            int wv = (lane < 16) ? wsums[lane] : 0;
            int wsc = wv;
#pragma unroll
            for (int d = 1; d < 16; d <<= 1) {
                int up = __shfl_up(wsc, d);
                if (lane >= d) wsc += up;
            }
            if (lane < 16) wsums[lane] = wsc - wv;
        }
        __syncthreads();
        int carry = carry_s;
        int inc = sc + wsums[wid] + carry;
        if (idx < Nn) { seg[idx + 1] = inc; pos[idx] = inc - v; }
        __syncthreads();
        if (t == 1023) carry_s = inc;
        __syncthreads();
    }
}

__global__ void k_scatter(const int* __restrict__ ei, int* __restrict__ pos,
                          int2* __restrict__ pse) {
    int i = blockIdx.x * 256 + threadIdx.x;
    if (i >= ET) return;
    int s, d;
    if (i < Ee) { s = ei[i]; d = ei[Ee + i]; } else { s = d = i - Ee; }
    int idx = atomicAdd(&pos[d], 1);
    pse[idx] = make_int2(s, i);
}

// ---------------- layer-0 only: als/ald = h @ Bs/Bd ----------------
__global__ void k_ab(const float* __restrict__ h, const float* __restrict__ Bs_l,
                     const float* __restrict__ Bd_l, float* __restrict__ als,
                     float* __restrict__ ald) {
    int idx = blockIdx.x * 256 + threadIdx.x;
    if (idx >= Nn * 8) return;
    int n = idx >> 3, slot = idx & 7;
    const float* B = (slot < 4) ? Bs_l : Bd_l;
    int hh = slot & 3;
    const float4* hr = (const float4*)(h + (size_t)n * 128);
    float s = 0.f;
#pragma unroll 8
    for (int kb = 0; kb < 32; kb++) {
        float4 hv = hr[kb];
        s += hv.x * B[(4 * kb + 0) * 4 + hh] + hv.y * B[(4 * kb + 1) * 4 + hh]
           + hv.z * B[(4 * kb + 2) * 4 + hh] + hv.w * B[(4 * kb + 3) * 4 + hh];
    }
    if (slot < 4) als[n * 4 + hh] = s;
    else          ald[n * 4 + hh] = s;
}

// ---- per-layer agg: SINGLE-PASS no-max softmax; 2 waves/node, 2 nodes/block ----
__global__ __launch_bounds__(256) void k_agg3(
    const int2* __restrict__ pse, const int* __restrict__ seg,
    const float* __restrict__ als, const float* __restrict__ ald,
    const float* __restrict__ aleT_l, const float* __restrict__ lale_l,
    const unsigned short* __restrict__ hb, unsigned short* __restrict__ aggb) {
    __shared__ float part[2][512];
    __shared__ float pden[2][4];
    int t = threadIdx.x;
    int lane = t & 63;
    int wv = (t >> 6) & 1;
    int w = t >> 7;
    int n = blockIdx.x * 2 + w;
    int start = seg[n], end = seg[n + 1];
    int deg = end - start;
    int half = (deg + 1) >> 1;
    int s0 = start + wv * half;
    int e0 = wv ? end : start + half;
    int hp = lane >> 4;
    int cch = (lane & 15) * 8;
    float aldh = ald[n * 4 + hp];
    float llh = lale_l[hp];
    float den = 0.f;
    float4 acc0 = make_float4(0.f, 0.f, 0.f, 0.f);
    float4 acc1 = make_float4(0.f, 0.f, 0.f, 0.f);
    int i = s0;
    for (; i + 2 <= e0; i += 2) {
        int2 sa = pse[i], sb = pse[i + 1];
        float ala = sa.y < Ee ? aleT_l[(size_t)sa.y * 4 + hp] : llh;
        float alb = sb.y < Ee ? aleT_l[(size_t)sb.y * 4 + hp] : llh;
        float ava = als[sa.x * 4 + hp] + aldh + ala;
        float avb = als[sb.x * 4 + hp] + aldh + alb;
        ava = ava > 0.f ? ava : 0.2f * ava;
        avb = avb > 0.f ? avb : 0.2f * avb;
        float ea = __expf(fminf(ava, 60.f));
        float eb = __expf(fminf(avb, 60.f));
        den += ea + eb;
        uint4 ua = *(const uint4*)(hb + (size_t)sa.x * 128 + cch);
        uint4 ub = *(const uint4*)(hb + (size_t)sb.x * 128 + cch);
        acc0.x += ea * bflo(ua.x) + eb * bflo(ub.x);
        acc0.y += ea * bfhi(ua.x) + eb * bfhi(ub.x);
        acc0.z += ea * bflo(ua.y) + eb * bflo(ub.y);
        acc0.w += ea * bfhi(ua.y) + eb * bfhi(ub.y);
        acc1.x += ea * bflo(ua.z) + eb * bflo(ub.z);
        acc1.y += ea * bfhi(ua.z) + eb * bfhi(ub.z);
        acc1.z += ea * bflo(ua.w) + eb * bflo(ub.w);
        acc1.w += ea * bfhi(ua.w) + eb * bfhi(ub.w);
    }
    if (i < e0) {
        int2 sa = pse[i];
        float ala = sa.y < Ee ? aleT_l[(size_t)sa.y * 4 + hp] : llh;
        float ava = als[sa.x * 4 + hp] + aldh + ala;
        ava = ava > 0.f ? ava : 0.2f * ava;
        float ea = __expf(fminf(ava, 60.f));
        den += ea;
        uint4 ua = *(const uint4*)(hb + (size_t)sa.x * 128 + cch);
        acc0.x += ea * bflo(ua.x); acc0.y += ea * bfhi(ua.x);
        acc0.z += ea * bflo(ua.y); acc0.w += ea * bfhi(ua.y);
        acc1.x += ea * bflo(ua.z); acc1.y += ea * bfhi(ua.z);
        acc1.z += ea * bflo(ua.w); acc1.w += ea * bfhi(ua.w);
    }
    // merge the 2 waves
    if (wv == 1) {
        *(float4*)&part[w][lane * 8] = acc0;
        *(float4*)&part[w][lane * 8 + 4] = acc1;
        if ((lane & 15) == 0) pden[w][hp] = den;
    }
    __syncthreads();
    if (wv == 0) {
        float4 p0 = *(const float4*)&part[w][lane * 8];
        float4 p1 = *(const float4*)&part[w][lane * 8 + 4];
        float inv = 1.f / (den + pden[w][hp] + 1e-16f);
        acc0.x = (acc0.x + p0.x) * inv; acc0.y = (acc0.y + p0.y) * inv;
        acc0.z = (acc0.z + p0.z) * inv; acc0.w = (acc0.w + p0.w) * inv;
        acc1.x = (acc1.x + p1.x) * inv; acc1.y = (acc1.y + p1.y) * inv;
        acc1.z = (acc1.z + p1.z) * inv; acc1.w = (acc1.w + p1.w) * inv;
        ushort4 q0, q1;
        q0.x = f2bf(acc0.x); q0.y = f2bf(acc0.y); q0.z = f2bf(acc0.z); q0.w = f2bf(acc0.w);
        q1.x = f2bf(acc1.x); q1.y = f2bf(acc1.y); q1.z = f2bf(acc1.z); q1.w = f2bf(acc1.w);
        *(ushort4*)(aggb + (size_t)n * 512 + lane * 8) = q0;
        *(ushort4*)(aggb + (size_t)n * 512 + lane * 8 + 4) = q1;
    }
}

// ---- per-layer: h_new = LN(relu(aggcat @ Wsum + gbias) + h); + next-layer als/ald ----
__global__ __launch_bounds__(256) void k_post(
    const unsigned short* __restrict__ aggb, const unsigned short* __restrict__ WsumT_l,
    const float* __restrict__ gbias, const float* __restrict__ lnsc,
    const float* __restrict__ lnbi, float* __restrict__ h,
    unsigned short* __restrict__ hb, const float* __restrict__ Bs_n,
    const float* __restrict__ Bd_n, float* __restrict__ als, float* __restrict__ ald) {
    int t = threadIdx.x;
    int lane = t & 63, w = t >> 6;
    int n0 = (blockIdx.x * 4 + w) * 16;
    if (n0 >= Nn) return;
    int m = lane & 15, q = lane >> 4;
    v4f acc[8];
#pragma unroll
    for (int nt = 0; nt < 8; nt++) acc[nt] = (v4f){0.f, 0.f, 0.f, 0.f};
    const unsigned short* arow = aggb + (size_t)(n0 + m) * 512 + q * 8;
#pragma unroll 4
    for (int ks = 0; ks < 16; ks++) {
        v8s fa = *(const v8s*)(arow + ks * 32);
#pragma unroll
        for (int nt = 0; nt < 8; nt++) {
            int col = nt * 16 + m;
            v8s fb = *(const v8s*)(WsumT_l + (size_t)col * 512 + ks * 32 + q * 8);
            acc[nt] = __builtin_amdgcn_mfma_f32_16x16x32_bf16(fa, fb, acc[nt], 0, 0, 0);
        }
    }
    // epilogue: rows n0+q*4+r, cols nt*16+m
    float v[8][4];
    float s1[4] = {0.f, 0.f, 0.f, 0.f}, s2[4] = {0.f, 0.f, 0.f, 0.f};
#pragma unroll
    for (int nt = 0; nt < 8; nt++) {
        int col = nt * 16 + m;
        float b = gbias[col];
#pragma unroll
        for (int r = 0; r < 4; r++) {
            int row = n0 + q * 4 + r;
            float val = h[(size_t)row * 128 + col] + fmaxf(acc[nt][r] + b, 0.f);
            v[nt][r] = val;
            s1[r] += val; s2[r] += val * val;
        }
    }
#pragma unroll
    for (int d = 1; d <= 8; d <<= 1) {
#pragma unroll
        for (int r = 0; r < 4; r++) {
            s1[r] += __shfl_xor(s1[r], d);
            s2[r] += __shfl_xor(s2[r], d);
        }
    }
    float o8[8][4];
#pragma unroll
    for (int r = 0; r < 4; r++) {
        float mean = s1[r] * (1.f / 128.f);
        float var = s2[r] * (1.f / 128.f) - mean * mean;
        float rinv = rsqrtf(var + 1e-5f);
        int row = n0 + q * 4 + r;
#pragma unroll
        for (int nt = 0; nt < 8; nt++) {
            int col = nt * 16 + m;
            float o = (v[nt][r] - mean) * rinv * lnsc[col] + lnbi[col];
            o8[nt][r] = o;
            h[(size_t)row * 128 + col] = o;
            hb[(size_t)row * 128 + col] = f2bf(o);
        }
    }
    // next-layer als/ald: sals[r][h] = sum_col o*Bs_n[col][h]
    float sal[4][4], sad[4][4];
#pragma unroll
    for (int r = 0; r < 4; r++) {
#pragma unroll
        for (int hh = 0; hh < 4; hh++) { sal[r][hh] = 0.f; sad[r][hh] = 0.f; }
    }
#pragma unroll
    for (int nt = 0; nt < 8; nt++) {
        int col = nt * 16 + m;
        float4 bs = *(const float4*)(Bs_n + col * 4);
        float4 bd = *(const float4*)(Bd_n + col * 4);
#pragma unroll
        for (int r = 0; r < 4; r++) {
            float o = o8[nt][r];
            sal[r][0] += o * bs.x; sal[r][1] += o * bs.y;
            sal[r][2] += o * bs.z; sal[r][3] += o * bs.w;
            sad[r][0] += o * bd.x; sad[r][1] += o * bd.y;
            sad[r][2] += o * bd.z; sad[r][3] += o * bd.w;
        }
    }
#pragma unroll
    for (int d = 1; d <= 8; d <<= 1) {
#pragma unroll
        for (int r = 0; r < 4; r++) {
#pragma unroll
            for (int hh = 0; hh < 4; hh++) {
                sal[r][hh] += __shfl_xor(sal[r][hh], d);
                sad[r][hh] += __shfl_xor(sad[r][hh], d);
            }
        }
    }
    if (m < 8) {
        int hh = m & 3;
#pragma unroll
        for (int r = 0; r < 4; r++) {
            int row = n0 + q * 4 + r;
            float va = (hh == 0) ? sal[r][0] : (hh == 1) ? sal[r][1] : (hh == 2) ? sal[r][2] : sal[r][3];
            float vd = (hh == 0) ? sad[r][0] : (hh == 1) ? sad[r][1] : (hh == 2) ? sad[r][2] : sad[r][3];
            if (m < 4) als[row * 4 + hh] = va;
            else       ald[row * 4 + hh] = vd;
        }
    }
}

// ---------------- output projection ----------------
__global__ __launch_bounds__(256) void k_out(
    const float* __restrict__ h, const float* __restrict__ ow,
    const float* __restrict__ ob, float* __restrict__ out) {
    __shared__ float4 hs4[8][32];
    int t = threadIdx.x;
    int n0 = blockIdx.x * 8;
    if (t < 256) {
        int i = t >> 5, kb = t & 31;
        hs4[i][kb] = *(const float4*)(h + (size_t)(n0 + i) * 128 + 4 * kb);
    }
    __syncthreads();
    float acc[8] = {0, 0, 0, 0, 0, 0, 0, 0};
    for (int kb = 0; kb < 32; kb++) {
        float w0 = ow[(4 * kb + 0) * 256 + t];
        float w1 = ow[(4 * kb + 1) * 256 + t];
        float w2 = ow[(4 * kb + 2) * 256 + t];
        float w3 = ow[(4 * kb + 3) * 256 + t];
#pragma unroll
        for (int i = 0; i < 8; i++) {
            float4 hv = hs4[i][kb];
            acc[i] += hv.x * w0 + hv.y * w1 + hv.z * w2 + hv.w * w3;
        }
    }
    float b = ob[t];
#pragma unroll
    for (int i = 0; i < 8; i++) out[(size_t)(n0 + i) * 256 + t] = acc[i] + b;
}

extern "C" void kernel_launch(void* const* d_in, const int* in_sizes, int n_in,
                              void* d_out, int out_size, void* d_ws, size_t ws_size,
                              hipStream_t stream) {
    const float* x    = (const float*)d_in[0];
    const int*   ei   = (const int*)d_in[1];
    const float* ea   = (const float*)d_in[2];
    const float* vnfc = (const float*)d_in[3];
    const float* nw   = (const float*)d_in[4];
    const float* nb   = (const float*)d_in[5];
    const float* eaw  = (const float*)d_in[6];
    const float* eab  = (const float*)d_in[7];
    const float* vw   = (const float*)d_in[8];
    const float* vb   = (const float*)d_in[9];
    const float* a1w  = (const float*)d_in[10];
    const float* a1b  = (const float*)d_in[11];
    const float* a2w  = (const float*)d_in[12];
    const float* a2b  = (const float*)d_in[13];
    const float* a3w  = (const float*)d_in[14];
    const float* a3b  = (const float*)d_in[15];
    const float* glw  = (const float*)d_in[16];
    const float* gas  = (const float*)d_in[17];
    const float* gad  = (const float*)d_in[18];
    const float* glew = (const float*)d_in[19];
    const float* gae  = (const float*)d_in[20];
    const float* gb   = (const float*)d_in[21];
    const float* lnsc = (const float*)d_in[22];
    const float* lnbi = (const float*)d_in[23];
    const float* ow   = (const float*)d_in[24];
    const float* ob   = (const float*)d_in[25];
    float* out = (float*)d_out;

    char* w = (char*)d_ws;
    size_t o = 0;
    auto allocf = [&](size_t cnt) { float* p = (float*)(w + o); o += ((cnt * 4 + 255) / 256) * 256; return p; };
    auto alloci = [&](size_t cnt) { int* p = (int*)(w + o); o += ((cnt * 4 + 255) / 256) * 256; return p; };
    auto allocu = [&](size_t cnt) { unsigned short* p = (unsigned short*)(w + o); o += ((cnt * 2 + 255) / 256) * 256; return p; };
    float* h      = allocf((size_t)Nn * 128);
    unsigned short* hb    = allocu((size_t)Nn * 128);
    unsigned short* aggb  = allocu((size_t)Nn * 512);
    unsigned short* WsumT = allocu((size_t)LL * 128 * 512);
    float* als    = allocf((size_t)Nn * 4);
    float* ald    = allocf((size_t)Nn * 4);
    float* aleT   = allocf((size_t)LL * Ee * 4);
    float* Bs     = allocf(3072);
    float* Bd     = allocf(3072);
    float* Be     = allocf(3072);
    float* E1     = allocf(1024);
    float* PB     = allocf(96);
    float* cB     = allocf(24);
    float* gsum   = allocf(8);
    float* lale   = allocf(32);
    int* seg  = alloci(Nn + 1);
    int* hist = alloci(Nn);
    int* pos  = alloci(Nn);
    int2* pse = (int2*)alloci((size_t)ET * 2);

    hipMemsetAsync(hist, 0, Nn * sizeof(int), stream);
    hipMemsetAsync(gsum, 0, 8 * sizeof(float), stream);

    k_node_embed<<<(Nn * 128 + 255) / 256, 256, 0, stream>>>(x, nw, nb, h, hb);
    k_small<<<1, 512, 0, stream>>>(vnfc, vw, vb, eab, a1w, a1b, eaw, E1);
    k_bmat<<<(LL * 128 * 4 + 255) / 256, 256, 0, stream>>>(glw, gas, gad, glew, gae, Bs, Bd, Be);
    k_wsum<<<(LL * 128 * 512 + 255) / 256, 256, 0, stream>>>(glw, WsumT);
    k_pb<<<1, 32, 0, stream>>>(eaw, eab, Be, PB, cB);
    k_edge<<<Ee / 256, 256, 0, stream>>>(ea, E1, a2w, a2b, a3w, a3b, PB, cB, aleT, gsum);
    k_hist<<<(ET + 255) / 256, 256, 0, stream>>>(ei, hist);
    k_scan<<<1, 1024, 0, stream>>>(hist, seg, pos);
    k_scatter<<<(ET + 255) / 256, 256, 0, stream>>>(ei, pos, pse);
    k_lale<<<1, 32, 0, stream>>>(gsum, PB, cB, lale);
    k_ab<<<(Nn * 8 + 255) / 256, 256, 0, stream>>>(h, Bs, Bd, als, ald);
    for (int l = 0; l < LL; l++) {
        int ln = (l + 1) % LL;
        k_agg3<<<Nn / 2, 256, 0, stream>>>(pse, seg, als, ald, aleT + (size_t)l * Ee * 4,
                                           lale + l * 4, hb, aggb);
        k_post<<<(625 + 3) / 4, 256, 0, stream>>>(aggb, WsumT + (size_t)l * 65536,
                                                  gb + l * 128, lnsc + l * 128, lnbi + l * 128,
                                                  h, hb, Bs + ln * 512, Bd + ln * 512, als, ald);
    }
    k_out<<<Nn / 8, 256, 0, stream>>>(h, ow, ob, out);
}